// Round 4
// baseline (54.331 us; speedup 1.0000x reference)
//
#include <hip/hip_runtime.h>

// PartitionPadding: ragged [N, D] rows (sorted segment ids) -> dense
// [B, max_atoms, D] zero-padded tensor. Single fused output-centric kernel:
// each block binary-searches the sorted indicator for its molecule's
// [start, end) (L1/L2-resident 256 KB array), then streams the slab.
// Every output element is written every call (harness poisons d_out once).

#define BATCH 512
#define UNROLL 8
#define TPB 256

typedef float f32x4 __attribute__((ext_vector_type(4)));  // native vec for nontemporal builtin

__global__ void gather_pad_fused(const f32x4* __restrict__ in,
                                 const int* __restrict__ mol,
                                 f32x4* __restrict__ out,
                                 int n, int row4, int nxfull) {
    const int m = blockIdx.y;

    // starts[m], starts[m+1] via lower_bound on the sorted indicator.
    __shared__ int sh[2];
    if (threadIdx.x < 2) {
        const int target = m + threadIdx.x;
        int lo = 0, hi = n;                  // first i with mol[i] >= target
        while (lo < hi) {
            const int mid = (lo + hi) >> 1;
            if (mol[mid] < target) lo = mid + 1; else hi = mid;
        }
        sh[threadIdx.x] = lo;
    }
    __syncthreads();
    const int s = sh[0];
    const int cnt = sh[1] - sh[0];

    // Flat within-slab float4 index j = a*128 + dd4  ->  src = in + s*128 + j
    // (atoms of a molecule are contiguous). Only the pad predicate needs a.
    const f32x4* __restrict__ inm = in + (long long)s * 128;
    f32x4* __restrict__ outm = out + (long long)m * row4;

    const int j0 = blockIdx.x * (TPB * UNROLL) + threadIdx.x;
    if (blockIdx.x < nxfull) {
        // Block fully in range: no j bounds checks -> 8 back-to-back
        // predicated loads + 8 nt stores.
        #pragma unroll
        for (int u = 0; u < UNROLL; ++u) {
            const int j = j0 + u * TPB;
            const int a = j >> 7;            // d4 == 128
            f32x4 v = (f32x4)(0.f);
            if (a < cnt) v = inm[j];         // predicated: OOB rows must not load
            __builtin_nontemporal_store(v, &outm[j]);
        }
    } else {
        #pragma unroll
        for (int u = 0; u < UNROLL; ++u) {
            const int j = j0 + u * TPB;
            if (j < row4) {
                const int a = j >> 7;
                f32x4 v = (f32x4)(0.f);
                if (a < cnt) v = inm[j];
                __builtin_nontemporal_store(v, &outm[j]);
            }
        }
    }
}

extern "C" void kernel_launch(void* const* d_in, const int* in_sizes, int n_in,
                              void* d_out, int out_size, void* d_ws, size_t ws_size,
                              hipStream_t stream) {
    const float* atom_features = (const float*)d_in[0];
    const int* mol = (const int*)d_in[1];
    float* out = (float*)d_out;

    const int n = in_sizes[1];                 // 65536 atoms
    const int d = in_sizes[0] / n;             // 512 features
    const int max_atoms = out_size / (BATCH * d);
    const int d4 = d / 4;                      // 128
    const int row4 = max_atoms * d4;           // float4s per molecule slab

    const int span = TPB * UNROLL;             // 2048 float4s per block
    const int nx = (row4 + span - 1) / span;
    const int nxfull = row4 / span;            // blocks with no tail

    dim3 grid(nx, BATCH);
    gather_pad_fused<<<grid, TPB, 0, stream>>>(
        (const f32x4*)atom_features, mol, (f32x4*)out, n, row4, nxfull);
}